// Round 2
// baseline (1814.788 us; speedup 1.0000x reference)
//
#include <hip/hip_runtime.h>
#include <stdint.h>
#include <stddef.h>

#define N_ 2048
#define D_ 64
#define INNER_ 32
#define HIDDEN_ 2048
#define CLASSES_ 10
#define P_ 2016
#define K_ (P_ * INNER_)      // 64512
#define SPLITK 4
#define KCHUNK (K_ / SPLITK)  // 16128
#define BM 128
#define BN 128
#define BK 32

typedef __bf16 bf16x8 __attribute__((ext_vector_type(8)));
typedef __bf16 bf16x4 __attribute__((ext_vector_type(4)));
typedef float f32x4v __attribute__((ext_vector_type(4)));
typedef float f32x2v __attribute__((ext_vector_type(2)));
typedef __attribute__((address_space(1))) void gvoid_t;
typedef __attribute__((address_space(3))) void lvoid_t;

// ---------------- stage 1: u[n, p*32+i] = relu(x[n,ii]*Wu[p,0,i] + x[n,jj]*Wu[p,1,i] + bu[p,i]) ----
__global__ __launch_bounds__(256) void k_u(const float* __restrict__ x,
                                           const float* __restrict__ Wu,
                                           const float* __restrict__ bu,
                                           __bf16* __restrict__ u) {
  const int n = blockIdx.y;
  const int t = threadIdx.x;
  __shared__ float xs[D_];
  if (t < D_) xs[t] = x[(size_t)n * D_ + t];
  __syncthreads();
  const int k0 = blockIdx.x * 1024 + t * 4;  // 4 consecutive k, same pair p
  const int p  = k0 >> 5;
  const int i0 = k0 & 31;
  int ii = (int)floorf((127.0f - sqrtf(16129.0f - 8.0f * (float)p)) * 0.5f);
  int off = ii * 63 - (ii * (ii - 1)) / 2;
  while (p >= off + (63 - ii)) { off += 63 - ii; ++ii; }
  while (p < off)              { --ii; off -= 63 - ii; }
  const int jj = (p - off) + ii + 1;
  const float xi = xs[ii], xj = xs[jj];
  const float4 w0 = *(const float4*)(Wu + (size_t)p * 64 + i0);
  const float4 w1 = *(const float4*)(Wu + (size_t)p * 64 + 32 + i0);
  const float4 bb = *(const float4*)(bu + (size_t)p * 32 + i0);
  bf16x4 r;
  r[0] = (__bf16)fmaxf(fmaf(xi, w0.x, fmaf(xj, w1.x, bb.x)), 0.0f);
  r[1] = (__bf16)fmaxf(fmaf(xi, w0.y, fmaf(xj, w1.y, bb.y)), 0.0f);
  r[2] = (__bf16)fmaxf(fmaf(xi, w0.z, fmaf(xj, w1.z, bb.z)), 0.0f);
  r[3] = (__bf16)fmaxf(fmaf(xi, w0.w, fmaf(xj, w1.w, bb.w)), 0.0f);
  *(bf16x4*)(u + (size_t)n * K_ + k0) = r;
}

// ---------------- stage 1b: WvT[h][k] = bf16(Wv[k][h]) — LDS tile transpose+convert ----
__global__ __launch_bounds__(256) void k_tr(const float* __restrict__ Wv,
                                            __bf16* __restrict__ BT) {
  __shared__ float ls[64][65];  // +1 pad: phase-2 column reads 2-way (free)
  const int t = threadIdx.x;
  const int k0 = blockIdx.x * 64, h0 = blockIdx.y * 64;
  const int c4 = (t & 15) * 4, r0 = t >> 4;
#pragma unroll
  for (int s = 0; s < 4; ++s) {
    const int r = r0 + 16 * s;
    const float4 vv = *(const float4*)(Wv + (size_t)(k0 + r) * HIDDEN_ + h0 + c4);
    ls[r][c4] = vv.x; ls[r][c4 + 1] = vv.y; ls[r][c4 + 2] = vv.z; ls[r][c4 + 3] = vv.w;
  }
  __syncthreads();
#pragma unroll
  for (int s = 0; s < 4; ++s) {
    const int h = r0 + 16 * s;
    bf16x4 o;
    o[0] = (__bf16)ls[c4][h];     o[1] = (__bf16)ls[c4 + 1][h];
    o[2] = (__bf16)ls[c4 + 2][h]; o[3] = (__bf16)ls[c4 + 3][h];
    *(bf16x4*)(BT + (size_t)(h0 + h) * K_ + k0 + c4) = o;
  }
}

// ---------------- stage 2 (main): m97-style symmetric GEMM, A and B both bf16 via global_load_lds ----
// XOR swizzle: LDS chunk (row, c) holds global k-chunk c^(row&3); frag read col = (q^(l15&3))*8.
// Turns the 4-way frag-read bank conflict (row stride 64 B) into a free 2-way.
__global__ __launch_bounds__(256) void k_gemm2(const __bf16* __restrict__ A,   // u [N_][K_]
                                               const __bf16* __restrict__ BT,  // WvT [HIDDEN_][K_]
                                               float* __restrict__ part) {
  __shared__ __bf16 As[BM][BK];  // 8 KB, unpadded (global_load_lds: contiguous lane*16)
  __shared__ __bf16 Bs[BN][BK];  // 8 KB

  const int t = threadIdx.x;
  const int lane = t & 63;
  const int w = t >> 6, wm = w >> 1, wn = w & 1;
  const int l15 = lane & 15, q = lane >> 4;
  const int bn = blockIdx.x, bm = blockIdx.y, kc = blockIdx.z;
  const int mbase = bm * BM, hbase = bn * BN;

  const int kx = (q ^ (l15 & 3)) * 8;  // swizzled frag column (loop-invariant)
  const bf16x8* ap[4];
  const bf16x8* bp[4];
#pragma unroll
  for (int mf = 0; mf < 4; ++mf) ap[mf] = (const bf16x8*)&As[wm * 64 + mf * 16 + l15][kx];
#pragma unroll
  for (int nf = 0; nf < 4; ++nf) bp[nf] = (const bf16x8*)&Bs[wn * 64 + nf * 16 + l15][kx];

  // staging pointers: chunk flat = r*256 + t; row = flat>>2; global col chunk = (flat&3)^(row&3)
  const __bf16* gA[2];
  const __bf16* gB[2];
  void* lA[2];
  void* lB[2];
#pragma unroll
  for (int r = 0; r < 2; ++r) {
    const int flat = r * 256 + t;
    const int row = flat >> 2;
    const int gc = (flat & 3) ^ (row & 3);
    gA[r] = A + (size_t)(mbase + row) * K_ + kc * KCHUNK + gc * 8;
    gB[r] = BT + (size_t)(hbase + row) * K_ + kc * KCHUNK + gc * 8;
    lA[r] = (char*)&As[0][0] + (size_t)(r * 256 + (t & ~63)) * 16;
    lB[r] = (char*)&Bs[0][0] + (size_t)(r * 256 + (t & ~63)) * 16;
  }

  f32x4v acc[4][4] = {};

  const int ksteps = KCHUNK / BK;  // 504
  for (int ks = 0; ks < ksteps; ++ks) {
    __syncthreads();  // prev iteration's frag reads done before overwrite
#pragma unroll
    for (int r = 0; r < 2; ++r) {
      __builtin_amdgcn_global_load_lds((gvoid_t*)(uintptr_t)gA[r],
                                       (lvoid_t*)(uint32_t)(uintptr_t)lA[r], 16, 0, 0);
      __builtin_amdgcn_global_load_lds((gvoid_t*)(uintptr_t)gB[r],
                                       (lvoid_t*)(uint32_t)(uintptr_t)lB[r], 16, 0, 0);
      gA[r] += BK;
      gB[r] += BK;
    }
    __syncthreads();  // staging visible (compiler drains vmcnt before barrier)

    bf16x8 av[4], bv4[4];
#pragma unroll
    for (int mf = 0; mf < 4; ++mf) av[mf] = *ap[mf];
#pragma unroll
    for (int nf = 0; nf < 4; ++nf) bv4[nf] = *bp[nf];
#pragma unroll
    for (int mf = 0; mf < 4; ++mf)
#pragma unroll
      for (int nf = 0; nf < 4; ++nf)
        acc[mf][nf] = __builtin_amdgcn_mfma_f32_16x16x32_bf16(av[mf], bv4[nf], acc[mf][nf], 0, 0, 0);
  }

  float* op = part + ((size_t)kc * N_ + mbase + wm * 64) * HIDDEN_ + hbase + wn * 64;
#pragma unroll
  for (int mf = 0; mf < 4; ++mf)
#pragma unroll
    for (int nf = 0; nf < 4; ++nf)
#pragma unroll
      for (int r = 0; r < 4; ++r)
        op[(size_t)(mf * 16 + q * 4 + r) * HIDDEN_ + nf * 16 + l15] = acc[mf][nf][r];
}

// ---------------- stage 2 (fallback, ws too small): in-kernel B convert, conflict-fixed ----
__global__ __launch_bounds__(256) void k_gemm_fb(const __bf16* __restrict__ A,
                                                 const float* __restrict__ Bv,
                                                 float* __restrict__ part) {
  __shared__ __bf16 As[BM][BK];
  __shared__ __bf16 BsT[BN][36];  // row stride 72 B: transpose writes conflict-free, reads 2-way

  const int t = threadIdx.x;
  const int lane = t & 63;
  const int w = t >> 6, wm = w >> 1, wn = w & 1;
  const int l15 = lane & 15, q = lane >> 4;
  const int bn = blockIdx.x, bm = blockIdx.y, kc = blockIdx.z;
  const int mbase = bm * BM, hbase = bn * BN;
  const int n0 = (t & 63) * 2;
  const int kq = t >> 6;
  const int kx = (q ^ (l15 & 3)) * 8;

  const bf16x8* ap[4];
  const bf16x8* bp[4];
#pragma unroll
  for (int mf = 0; mf < 4; ++mf) ap[mf] = (const bf16x8*)&As[wm * 64 + mf * 16 + l15][kx];
#pragma unroll
  for (int nf = 0; nf < 4; ++nf) bp[nf] = (const bf16x8*)&BsT[wn * 64 + nf * 16 + l15][q * 8];

  f32x4v acc[4][4] = {};

  const int ksteps = KCHUNK / BK;
  for (int ks = 0; ks < ksteps; ++ks) {
    const int kbase = kc * KCHUNK + ks * BK;
    const float* gb = Bv + (size_t)(kbase + kq * 8) * HIDDEN_ + hbase + n0;
    f32x2v f[8];
#pragma unroll
    for (int qq = 0; qq < 8; ++qq) f[qq] = *(const f32x2v*)(gb + (size_t)qq * HIDDEN_);

    __syncthreads();
#pragma unroll
    for (int r = 0; r < 2; ++r) {
      const int flat = r * 256 + t;
      const int row = flat >> 2;
      const int gc = (flat & 3) ^ (row & 3);
      const __bf16* ga = A + (size_t)(mbase + row) * K_ + kbase + gc * 8;
      void* lp = (char*)&As[0][0] + (size_t)(r * 256 + (t & ~63)) * 16;
      __builtin_amdgcn_global_load_lds((gvoid_t*)(uintptr_t)ga,
                                       (lvoid_t*)(uint32_t)(uintptr_t)lp, 16, 0, 0);
    }
    bf16x8 c0, c1;
#pragma unroll
    for (int qq = 0; qq < 8; ++qq) { c0[qq] = (__bf16)f[qq][0]; c1[qq] = (__bf16)f[qq][1]; }
    *(bf16x8*)&BsT[n0][kq * 8]     = c0;
    *(bf16x8*)&BsT[n0 + 1][kq * 8] = c1;

    __syncthreads();

    bf16x8 av[4], bv4[4];
#pragma unroll
    for (int mf = 0; mf < 4; ++mf) av[mf] = *ap[mf];
#pragma unroll
    for (int nf = 0; nf < 4; ++nf) bv4[nf] = *bp[nf];
#pragma unroll
    for (int mf = 0; mf < 4; ++mf)
#pragma unroll
      for (int nf = 0; nf < 4; ++nf)
        acc[mf][nf] = __builtin_amdgcn_mfma_f32_16x16x32_bf16(av[mf], bv4[nf], acc[mf][nf], 0, 0, 0);
  }

  float* op = part + ((size_t)kc * N_ + mbase + wm * 64) * HIDDEN_ + hbase + wn * 64;
#pragma unroll
  for (int mf = 0; mf < 4; ++mf)
#pragma unroll
    for (int nf = 0; nf < 4; ++nf)
#pragma unroll
      for (int r = 0; r < 4; ++r)
        op[(size_t)(mf * 16 + q * 4 + r) * HIDDEN_ + nf * 16 + l15] = acc[mf][nf][r];
}

// ---------------- stage 3: v = relu(sum(partials) + bv) ----------------
__global__ __launch_bounds__(256) void k_reduce(const float* __restrict__ part,
                                                const float* __restrict__ bv,
                                                float* __restrict__ v) {
  const size_t i = ((size_t)blockIdx.x * 256 + threadIdx.x) * 4;
  f32x4v s = *(const f32x4v*)(part + i);
  s += *(const f32x4v*)(part + (size_t)1 * N_ * HIDDEN_ + i);
  s += *(const f32x4v*)(part + (size_t)2 * N_ * HIDDEN_ + i);
  s += *(const f32x4v*)(part + (size_t)3 * N_ * HIDDEN_ + i);
  s += *(const f32x4v*)(bv + (i & (HIDDEN_ - 1)));
  s[0] = fmaxf(s[0], 0.0f);
  s[1] = fmaxf(s[1], 0.0f);
  s[2] = fmaxf(s[2], 0.0f);
  s[3] = fmaxf(s[3], 0.0f);
  *(f32x4v*)(v + i) = s;
}

// ---------------- stage 4: out = v @ Wo + bo (wave per row) ----------------
__global__ __launch_bounds__(256) void k_out(const float* __restrict__ v,
                                             const float* __restrict__ Wo,
                                             const float* __restrict__ bo,
                                             float* __restrict__ out) {
  const int lane = threadIdx.x & 63;
  const int n = blockIdx.x * 4 + (threadIdx.x >> 6);
  float acc[CLASSES_];
#pragma unroll
  for (int c = 0; c < CLASSES_; ++c) acc[c] = 0.0f;
  for (int h0 = lane * 4; h0 < HIDDEN_; h0 += 256) {
    const f32x4v vv = *(const f32x4v*)(v + (size_t)n * HIDDEN_ + h0);
#pragma unroll
    for (int qq = 0; qq < 4; ++qq) {
      const float s = vv[qq];
      const float* wo = Wo + (size_t)(h0 + qq) * CLASSES_;
#pragma unroll
      for (int c = 0; c < CLASSES_; ++c) acc[c] = fmaf(s, wo[c], acc[c]);
    }
  }
#pragma unroll
  for (int c = 0; c < CLASSES_; ++c) {
#pragma unroll
    for (int o = 32; o > 0; o >>= 1) acc[c] += __shfl_down(acc[c], o);
  }
  if (lane == 0) {
#pragma unroll
    for (int c = 0; c < CLASSES_; ++c) out[(size_t)n * CLASSES_ + c] = acc[c] + bo[c];
  }
}

extern "C" void kernel_launch(void* const* d_in, const int* in_sizes, int n_in,
                              void* d_out, int out_size, void* d_ws, size_t ws_size,
                              hipStream_t stream) {
  const float* x  = (const float*)d_in[0];
  const float* Wu = (const float*)d_in[1];
  const float* bu = (const float*)d_in[2];
  const float* Wv = (const float*)d_in[3];
  const float* bv = (const float*)d_in[4];
  const float* Wo = (const float*)d_in[5];
  const float* bo = (const float*)d_in[6];
  float* out = (float*)d_out;

  char* ws = (char*)d_ws;
  const size_t SZ_BT = (size_t)HIDDEN_ * K_ * 2;          // 264,241,152
  const size_t SZ_U  = (size_t)N_ * K_ * 2;               // 264,241,152
  const size_t SZ_P  = (size_t)SPLITK * N_ * HIDDEN_ * 4; // 67,108,864
  const size_t NEED  = SZ_BT + SZ_U + SZ_P;               // 595,591,168

  if (ws_size >= NEED) {
    // main path: WvT @0, u after, part after; v aliases WvT (dead after gemm)
    __bf16* BT  = (__bf16*)ws;
    __bf16* u   = (__bf16*)(ws + SZ_BT);
    float* part = (float*)(ws + SZ_BT + SZ_U);
    float* v    = (float*)ws;

    k_u<<<dim3(K_ / 1024, N_), 256, 0, stream>>>(x, Wu, bu, u);
    k_tr<<<dim3(K_ / 64, HIDDEN_ / 64), 256, 0, stream>>>(Wv, BT);
    k_gemm2<<<dim3(HIDDEN_ / BN, N_ / BM, SPLITK), 256, 0, stream>>>(u, BT, part);
    k_reduce<<<dim3((N_ * HIDDEN_) / 1024), 256, 0, stream>>>(part, bv, v);
    k_out<<<dim3(N_ / 4), 256, 0, stream>>>(v, Wo, bo, out);
  } else {
    // fallback (348 MB): round-1 layout, conflict-fixed gemm
    __bf16* u   = (__bf16*)ws;
    float* part = (float*)(ws + SZ_U);
    float* v    = (float*)(ws + SZ_U + SZ_P);

    k_u<<<dim3(K_ / 1024, N_), 256, 0, stream>>>(x, Wu, bu, u);
    k_gemm_fb<<<dim3(HIDDEN_ / BN, N_ / BM, SPLITK), 256, 0, stream>>>(u, Wv, part);
    k_reduce<<<dim3((N_ * HIDDEN_) / 1024), 256, 0, stream>>>(part, bv, v);
    k_out<<<dim3(N_ / 4), 256, 0, stream>>>(v, Wo, bo, out);
  }
}

// Round 3
// 1515.402 us; speedup vs baseline: 1.1976x; 1.1976x over previous
//
#include <hip/hip_runtime.h>
#include <stdint.h>
#include <stddef.h>

#define N_ 2048
#define D_ 64
#define INNER_ 32
#define HIDDEN_ 2048
#define CLASSES_ 10
#define P_ 2016
#define K_ (P_ * INNER_)      // 64512
#define SPLITK 4
#define KCHUNK (K_ / SPLITK)  // 16128
// fallback-kernel tile
#define BM 128
#define BN 128
#define BK 32
// main gemm tile
#define TBM 256
#define TBN 256
#define TBK 32

typedef __bf16 bf16x8 __attribute__((ext_vector_type(8)));
typedef __bf16 bf16x4 __attribute__((ext_vector_type(4)));
typedef float f32x16 __attribute__((ext_vector_type(16)));
typedef float f32x4v __attribute__((ext_vector_type(4)));
typedef float f32x2v __attribute__((ext_vector_type(2)));
typedef __attribute__((address_space(1))) void gvoid_t;
typedef __attribute__((address_space(3))) void lvoid_t;

// ---------------- stage 1: u[n, p*32+i] = relu(x[n,ii]*Wu[p,0,i] + x[n,jj]*Wu[p,1,i] + bu[p,i]) ----
__global__ __launch_bounds__(256) void k_u(const float* __restrict__ x,
                                           const float* __restrict__ Wu,
                                           const float* __restrict__ bu,
                                           __bf16* __restrict__ u) {
  const int n = blockIdx.y;
  const int t = threadIdx.x;
  __shared__ float xs[D_];
  if (t < D_) xs[t] = x[(size_t)n * D_ + t];
  __syncthreads();
  const int k0 = blockIdx.x * 1024 + t * 4;
  const int p  = k0 >> 5;
  const int i0 = k0 & 31;
  int ii = (int)floorf((127.0f - sqrtf(16129.0f - 8.0f * (float)p)) * 0.5f);
  int off = ii * 63 - (ii * (ii - 1)) / 2;
  while (p >= off + (63 - ii)) { off += 63 - ii; ++ii; }
  while (p < off)              { --ii; off -= 63 - ii; }
  const int jj = (p - off) + ii + 1;
  const float xi = xs[ii], xj = xs[jj];
  const float4 w0 = *(const float4*)(Wu + (size_t)p * 64 + i0);
  const float4 w1 = *(const float4*)(Wu + (size_t)p * 64 + 32 + i0);
  const float4 bb = *(const float4*)(bu + (size_t)p * 32 + i0);
  bf16x4 r;
  r[0] = (__bf16)fmaxf(fmaf(xi, w0.x, fmaf(xj, w1.x, bb.x)), 0.0f);
  r[1] = (__bf16)fmaxf(fmaf(xi, w0.y, fmaf(xj, w1.y, bb.y)), 0.0f);
  r[2] = (__bf16)fmaxf(fmaf(xi, w0.z, fmaf(xj, w1.z, bb.z)), 0.0f);
  r[3] = (__bf16)fmaxf(fmaf(xi, w0.w, fmaf(xj, w1.w, bb.w)), 0.0f);
  *(bf16x4*)(u + (size_t)n * K_ + k0) = r;
}

// ---------------- stage 1b: WvT[h][k] = bf16(Wv[k][h]) — 64x64 LDS transpose, 16B / 128B-coalesced stores ----
__global__ __launch_bounds__(256) void k_tr(const float* __restrict__ Wv,
                                            __bf16* __restrict__ BT) {
  __shared__ float ls[64][65];
  const int t = threadIdx.x;
  const int k0 = blockIdx.x * 64, h0 = blockIdx.y * 64;
  const int c4 = (t & 15) * 4, r0 = t >> 4;
#pragma unroll
  for (int s = 0; s < 4; ++s) {
    const int r = r0 + 16 * s;
    const float4 vv = *(const float4*)(Wv + (size_t)(k0 + r) * HIDDEN_ + h0 + c4);
    ls[r][c4] = vv.x; ls[r][c4 + 1] = vv.y; ls[r][c4 + 2] = vv.z; ls[r][c4 + 3] = vv.w;
  }
  __syncthreads();
#pragma unroll
  for (int s = 0; s < 2; ++s) {
    const int item = s * 256 + t;
    const int h = item >> 3;      // 0..63
    const int kch = item & 7;     // 8-elem k chunk
    bf16x8 o;
#pragma unroll
    for (int j = 0; j < 8; ++j) o[j] = (__bf16)ls[kch * 8 + j][h];
    *(bf16x8*)(BT + (size_t)(h0 + h) * K_ + k0 + kch * 8) = o;
  }
}

// ---------------- stage 2 (main): 256x256 tile, 32x32x16 MFMA, dbuf LDS one-barrier pipeline ----
// swizzle g(row)=(row>>1)&3: LDS (row, cpos) holds global chunk cpos^g(row); frag read cpos=(c)^g(row).
// Within each b128 quarter-wave phase: (row&1, g(row)) covers all 8 16B start positions x2 -> free 2-way.
__global__ __launch_bounds__(512, 2) void k_gemm3(const __bf16* __restrict__ A,   // u [N_][K_]
                                                  const __bf16* __restrict__ BT,  // WvT [HIDDEN_][K_]
                                                  float* __restrict__ part) {
  __shared__ __align__(16) __bf16 lds[2][2][TBM][TBK];  // [buf][op][row][k] = 64 KB

  const int t = threadIdx.x;
  const int lane = t & 63;
  const int w = t >> 6;                 // 0..7
  const int wm = w & 3, wn = w >> 2;    // 4x2 wave grid, wave tile 64x128
  const int l31 = lane & 31, khalf = lane >> 5;

  // XCD-aware swizzle: XCD g hosts bm in [(g>>2)*4,+4), bn in [(g&3)*2,+2), all kc
  const int id = blockIdx.x;
  const int g = id & 7, s = id >> 3;
  const int bm = ((g >> 2) << 2) + (s & 3);
  const int bn = ((g & 3) << 1) + ((s >> 2) & 1);
  const int kc = s >> 3;
  const int mbase = bm * TBM, hbase = bn * TBN;

  // staging pointers: flat = r*512+t; row=flat>>2; cpos=flat&3; global chunk gc=cpos^((row>>1)&3)
  const __bf16* gA[2];
  const __bf16* gB[2];
  uint32_t lOff[2];
#pragma unroll
  for (int r = 0; r < 2; ++r) {
    const int flat = r * 512 + t;
    const int row = flat >> 2;
    const int gc = (flat & 3) ^ ((row >> 1) & 3);
    gA[r] = A + (size_t)(mbase + row) * K_ + kc * KCHUNK + gc * 8;
    gB[r] = BT + (size_t)(hbase + row) * K_ + kc * KCHUNK + gc * 8;
    lOff[r] = (uint32_t)((r * 512 + (t & ~63)) * 16);  // wave-uniform base; HW adds lane*16
  }

  // fragment LDS element offsets within one buffer (A plane at 0, B plane at 8192)
  int aoff[2][2], boff[4][2];
#pragma unroll
  for (int mf = 0; mf < 2; ++mf)
#pragma unroll
    for (int ss = 0; ss < 2; ++ss) {
      const int row = wm * 64 + mf * 32 + l31;
      const int cpos = (ss * 2 + khalf) ^ ((row >> 1) & 3);
      aoff[mf][ss] = row * TBK + cpos * 8;
    }
#pragma unroll
  for (int nf = 0; nf < 4; ++nf)
#pragma unroll
    for (int ss = 0; ss < 2; ++ss) {
      const int row = wn * 128 + nf * 32 + l31;
      const int cpos = (ss * 2 + khalf) ^ ((row >> 1) & 3);
      boff[nf][ss] = TBM * TBK + row * TBK + cpos * 8;
    }

  f32x16 acc[2][4] = {};
  char* ldsbase = (char*)&lds[0][0][0][0];

  // prologue: stage kstep 0 into buf 0
#pragma unroll
  for (int r = 0; r < 2; ++r) {
    __builtin_amdgcn_global_load_lds((gvoid_t*)(uintptr_t)gA[r],
                                     (lvoid_t*)(uint32_t)(uintptr_t)(ldsbase + lOff[r]), 16, 0, 0);
    __builtin_amdgcn_global_load_lds((gvoid_t*)(uintptr_t)gB[r],
                                     (lvoid_t*)(uint32_t)(uintptr_t)(ldsbase + 16384 + lOff[r]), 16, 0, 0);
    gA[r] += TBK;
    gB[r] += TBK;
  }

  const int ksteps = KCHUNK / TBK;  // 504
  for (int ks = 0; ks < ksteps; ++ks) {
    const int cur = ks & 1;
    __syncthreads();  // drains vmcnt: buf[cur] staging complete; prior frag reads drained

    // frag reads from buf[cur] (issued before prefetch so lgkm waits don't block the gll issue)
    const __bf16* plane = (const __bf16*)(ldsbase + (size_t)cur * 32768);
    bf16x8 av[2][2], bv4[4][2];
#pragma unroll
    for (int mf = 0; mf < 2; ++mf)
#pragma unroll
      for (int ss = 0; ss < 2; ++ss) av[mf][ss] = *(const bf16x8*)(plane + aoff[mf][ss]);
#pragma unroll
    for (int nf = 0; nf < 4; ++nf)
#pragma unroll
      for (int ss = 0; ss < 2; ++ss) bv4[nf][ss] = *(const bf16x8*)(plane + boff[nf][ss]);

    // prefetch next kstep into buf[cur^1]; stays in flight through this compute phase
    if (ks + 1 < ksteps) {
      char* dst = ldsbase + (size_t)(cur ^ 1) * 32768;
#pragma unroll
      for (int r = 0; r < 2; ++r) {
        __builtin_amdgcn_global_load_lds((gvoid_t*)(uintptr_t)gA[r],
                                         (lvoid_t*)(uint32_t)(uintptr_t)(dst + lOff[r]), 16, 0, 0);
        __builtin_amdgcn_global_load_lds((gvoid_t*)(uintptr_t)gB[r],
                                         (lvoid_t*)(uint32_t)(uintptr_t)(dst + 16384 + lOff[r]), 16, 0, 0);
        gA[r] += TBK;
        gB[r] += TBK;
      }
    }

#pragma unroll
    for (int ss = 0; ss < 2; ++ss)
#pragma unroll
      for (int mf = 0; mf < 2; ++mf)
#pragma unroll
        for (int nf = 0; nf < 4; ++nf)
          acc[mf][nf] = __builtin_amdgcn_mfma_f32_32x32x16_bf16(av[mf][ss], bv4[nf][ss],
                                                                acc[mf][nf], 0, 0, 0);
  }

  // epilogue: 32x32 C/D layout col=lane&31, row=(reg&3)+8*(reg>>2)+4*(lane>>5)
  float* op = part + ((size_t)kc * N_ + mbase + wm * 64) * HIDDEN_ + hbase + wn * 128;
#pragma unroll
  for (int mf = 0; mf < 2; ++mf)
#pragma unroll
    for (int nf = 0; nf < 4; ++nf)
#pragma unroll
      for (int rg = 0; rg < 16; ++rg) {
        const int row = mf * 32 + (rg & 3) + 8 * (rg >> 2) + 4 * khalf;
        op[(size_t)row * HIDDEN_ + nf * 32 + l31] = acc[mf][nf][rg];
      }
}

// ---------------- stage 2 (fallback, ws too small): in-kernel B convert ----
__global__ __launch_bounds__(256) void k_gemm_fb(const __bf16* __restrict__ A,
                                                 const float* __restrict__ Bv,
                                                 float* __restrict__ part) {
  __shared__ __bf16 As[BM][BK];
  __shared__ __bf16 BsT[BN][36];

  const int t = threadIdx.x;
  const int lane = t & 63;
  const int w = t >> 6, wm = w >> 1, wn = w & 1;
  const int l15 = lane & 15, q = lane >> 4;
  const int bn = blockIdx.x, bm = blockIdx.y, kc = blockIdx.z;
  const int mbase = bm * BM, hbase = bn * BN;
  const int n0 = (t & 63) * 2;
  const int kq = t >> 6;
  const int kx = (q ^ ((l15 >> 1) & 3)) * 8;

  const bf16x8* ap[4];
  const bf16x8* bp[4];
#pragma unroll
  for (int mf = 0; mf < 4; ++mf) ap[mf] = (const bf16x8*)&As[wm * 64 + mf * 16 + l15][kx];
#pragma unroll
  for (int nf = 0; nf < 4; ++nf) bp[nf] = (const bf16x8*)&BsT[wn * 64 + nf * 16 + l15][q * 8];

  f32x4v acc[4][4] = {};

  const int ksteps = KCHUNK / BK;
  for (int ks = 0; ks < ksteps; ++ks) {
    const int kbase = kc * KCHUNK + ks * BK;
    const float* gb = Bv + (size_t)(kbase + kq * 8) * HIDDEN_ + hbase + n0;
    f32x2v f[8];
#pragma unroll
    for (int qq = 0; qq < 8; ++qq) f[qq] = *(const f32x2v*)(gb + (size_t)qq * HIDDEN_);

    __syncthreads();
#pragma unroll
    for (int r = 0; r < 2; ++r) {
      const int flat = r * 256 + t;
      const int row = flat >> 2;
      const int gc = (flat & 3) ^ ((row >> 1) & 3);
      const __bf16* ga = A + (size_t)(mbase + row) * K_ + kbase + gc * 8;
      void* lp = (char*)&As[0][0] + (size_t)(r * 256 + (t & ~63)) * 16;
      __builtin_amdgcn_global_load_lds((gvoid_t*)(uintptr_t)ga,
                                       (lvoid_t*)(uint32_t)(uintptr_t)lp, 16, 0, 0);
    }
    bf16x8 c0, c1;
#pragma unroll
    for (int qq = 0; qq < 8; ++qq) { c0[qq] = (__bf16)f[qq][0]; c1[qq] = (__bf16)f[qq][1]; }
    *(bf16x8*)&BsT[n0][kq * 8]     = c0;
    *(bf16x8*)&BsT[n0 + 1][kq * 8] = c1;

    __syncthreads();

    bf16x8 av[4], bv4[4];
#pragma unroll
    for (int mf = 0; mf < 4; ++mf) av[mf] = *ap[mf];
#pragma unroll
    for (int nf = 0; nf < 4; ++nf) bv4[nf] = *bp[nf];
#pragma unroll
    for (int mf = 0; mf < 4; ++mf)
#pragma unroll
      for (int nf = 0; nf < 4; ++nf)
        acc[mf][nf] = __builtin_amdgcn_mfma_f32_16x16x32_bf16(av[mf], bv4[nf], acc[mf][nf], 0, 0, 0);
  }

  float* op = part + ((size_t)kc * N_ + mbase + wm * 64) * HIDDEN_ + hbase + wn * 64;
#pragma unroll
  for (int mf = 0; mf < 4; ++mf)
#pragma unroll
    for (int nf = 0; nf < 4; ++nf)
#pragma unroll
      for (int r = 0; r < 4; ++r)
        op[(size_t)(mf * 16 + q * 4 + r) * HIDDEN_ + nf * 16 + l15] = acc[mf][nf][r];
}

// ---------------- stage 3: v = relu(sum(partials) + bv) ----------------
__global__ __launch_bounds__(256) void k_reduce(const float* __restrict__ part,
                                                const float* __restrict__ bv,
                                                float* __restrict__ v) {
  const size_t i = ((size_t)blockIdx.x * 256 + threadIdx.x) * 4;
  f32x4v s = *(const f32x4v*)(part + i);
  s += *(const f32x4v*)(part + (size_t)1 * N_ * HIDDEN_ + i);
  s += *(const f32x4v*)(part + (size_t)2 * N_ * HIDDEN_ + i);
  s += *(const f32x4v*)(part + (size_t)3 * N_ * HIDDEN_ + i);
  s += *(const f32x4v*)(bv + (i & (HIDDEN_ - 1)));
  s[0] = fmaxf(s[0], 0.0f);
  s[1] = fmaxf(s[1], 0.0f);
  s[2] = fmaxf(s[2], 0.0f);
  s[3] = fmaxf(s[3], 0.0f);
  *(f32x4v*)(v + i) = s;
}

// ---------------- stage 4: out = v @ Wo + bo (wave per row) ----------------
__global__ __launch_bounds__(256) void k_out(const float* __restrict__ v,
                                             const float* __restrict__ Wo,
                                             const float* __restrict__ bo,
                                             float* __restrict__ out) {
  const int lane = threadIdx.x & 63;
  const int n = blockIdx.x * 4 + (threadIdx.x >> 6);
  float acc[CLASSES_];
#pragma unroll
  for (int c = 0; c < CLASSES_; ++c) acc[c] = 0.0f;
  for (int h0 = lane * 4; h0 < HIDDEN_; h0 += 256) {
    const f32x4v vv = *(const f32x4v*)(v + (size_t)n * HIDDEN_ + h0);
#pragma unroll
    for (int qq = 0; qq < 4; ++qq) {
      const float s = vv[qq];
      const float* wo = Wo + (size_t)(h0 + qq) * CLASSES_;
#pragma unroll
      for (int c = 0; c < CLASSES_; ++c) acc[c] = fmaf(s, wo[c], acc[c]);
    }
  }
#pragma unroll
  for (int c = 0; c < CLASSES_; ++c) {
#pragma unroll
    for (int o = 32; o > 0; o >>= 1) acc[c] += __shfl_down(acc[c], o);
  }
  if (lane == 0) {
#pragma unroll
    for (int c = 0; c < CLASSES_; ++c) out[(size_t)n * CLASSES_ + c] = acc[c] + bo[c];
  }
}

extern "C" void kernel_launch(void* const* d_in, const int* in_sizes, int n_in,
                              void* d_out, int out_size, void* d_ws, size_t ws_size,
                              hipStream_t stream) {
  const float* x  = (const float*)d_in[0];
  const float* Wu = (const float*)d_in[1];
  const float* bu = (const float*)d_in[2];
  const float* Wv = (const float*)d_in[3];
  const float* bv = (const float*)d_in[4];
  const float* Wo = (const float*)d_in[5];
  const float* bo = (const float*)d_in[6];
  float* out = (float*)d_out;

  char* ws = (char*)d_ws;
  const size_t SZ_BT = (size_t)HIDDEN_ * K_ * 2;          // 264,241,152
  const size_t SZ_U  = (size_t)N_ * K_ * 2;               // 264,241,152
  const size_t SZ_P  = (size_t)SPLITK * N_ * HIDDEN_ * 4; // 67,108,864
  const size_t NEED  = SZ_BT + SZ_U + SZ_P;               // 595,591,168

  if (ws_size >= NEED) {
    __bf16* BT  = (__bf16*)ws;
    __bf16* u   = (__bf16*)(ws + SZ_BT);
    float* part = (float*)(ws + SZ_BT + SZ_U);
    float* v    = (float*)ws;  // aliases BT (dead after gemm)

    k_u<<<dim3(K_ / 1024, N_), 256, 0, stream>>>(x, Wu, bu, u);
    k_tr<<<dim3(K_ / 64, HIDDEN_ / 64), 256, 0, stream>>>(Wv, BT);
    k_gemm3<<<dim3((HIDDEN_ / TBN) * (N_ / TBM) * SPLITK), 512, 0, stream>>>(u, BT, part);
    k_reduce<<<dim3((N_ * HIDDEN_) / 1024), 256, 0, stream>>>(part, bv, v);
    k_out<<<dim3(N_ / 4), 256, 0, stream>>>(v, Wo, bo, out);
  } else {
    __bf16* u   = (__bf16*)ws;
    float* part = (float*)(ws + SZ_U);
    float* v    = (float*)(ws + SZ_U + SZ_P);

    k_u<<<dim3(K_ / 1024, N_), 256, 0, stream>>>(x, Wu, bu, u);
    k_gemm_fb<<<dim3(HIDDEN_ / BN, N_ / BM, SPLITK), 256, 0, stream>>>(u, Wv, part);
    k_reduce<<<dim3((N_ * HIDDEN_) / 1024), 256, 0, stream>>>(part, bv, v);
    k_out<<<dim3(N_ / 4), 256, 0, stream>>>(v, Wo, bo, out);
  }
}